// Round 1
// baseline (111.880 us; speedup 1.0000x reference)
//
#include <hip/hip_runtime.h>
#include <math.h>

#define B_  8
#define N_  128
#define T_  256
#define L_  32
#define H_  128
#define TT_ 224   // T - L

typedef float f2    __attribute__((ext_vector_type(2)));
typedef float f4    __attribute__((ext_vector_type(4)));
typedef float f32x4 __attribute__((ext_vector_type(4)));
typedef short bf16x8 __attribute__((ext_vector_type(8)));

#define L2E_  1.4426950408889634f
#define L2E2_ 2.8853900817779268f

__device__ __forceinline__ unsigned pk2bf(float a, float b) {   // RNE bf16 pack
    unsigned ua = __float_as_uint(a), ub = __float_as_uint(b);
    ua = (ua + 0x7FFFu + ((ua >> 16) & 1u)) >> 16;
    ub = (ub + 0x7FFFu + ((ub >> 16) & 1u)) >> 16;
    return ua | (ub << 16);
}
__device__ __forceinline__ float aexp2(float x) {
    float r; asm("v_exp_f32 %0, %1" : "=v"(r) : "v"(x)); return r;
}
__device__ __forceinline__ float aexp2n(float x) {
    float r; asm("v_exp_f32 %0, -%1" : "=v"(r) : "v"(x)); return r;
}
__device__ __forceinline__ float arcp(float x) {
    return __builtin_amdgcn_rcpf(x);
}

// ---------------------------------------------------------------------------
// Single fused kernel, grid (N,B)=1024 x 256. k_pre's work (W_ih -> bf16
// pre-scaled B-frags, wsum/bsum/bias fusion) is folded into the prologue:
//   - each lane builds its 6 B-frags straight from W_ih global (identical
//     arithmetic to the old k_pre, so numerics unchanged)
//   - wsum recomputed per block with coalesced f4 loads + LDS reduce
//   - workspace entirely unused; one launch instead of two; no HBM
//     round-trip of W3sw between kernels.
// Activation: 4 trans/element via merged reciprocal, exact algebra:
//   A=(1+e1)(e2+1), B=1+e3, R=rcp(A*B), t=em*R (em=e2-1),
//   c=t*B (= sig(gi)tanh(gg)), hh=t*Q(c^2) (= sig(go)*poly7tanh(c)).
// ---------------------------------------------------------------------------
__global__ __launch_bounds__(256)
__attribute__((amdgpu_waves_per_eu(4, 4)))
void k_main(const float* __restrict__ x,
            const float* __restrict__ W_ih,
            const float* __restrict__ b_ih, const float* __restrict__ b_hh,
            const float* __restrict__ W_fc, const float* __restrict__ b_fc,
            float* __restrict__ G, float* __restrict__ xhat) {
    const int n   = blockIdx.x;
    const int b   = blockIdx.y;
    const int tid = threadIdx.x;
    const int w    = tid >> 6;    // wave 0..3
    const int lane = tid & 63;
    const int col  = lane & 15;   // MFMA m/n index
    const int quad = lane >> 4;   // MFMA k-group / row-group

    __shared__ float xs[258];
    __shared__ unsigned xeo[2][128];
    __shared__ float xr[TT_];
    __shared__ uint4 xA[14 * 64];      // per-lane A-frags, 14 KB
    __shared__ float xh_part[4][TT_];
    __shared__ float hd_loc[H_];
    __shared__ float red[4];
    __shared__ f4 wpart[8][32];        // wsum partials, 4 KB
    __shared__ float ws_loc[H_];
    __shared__ float bp[2];
    __shared__ float bs_s;

    // ---- phase A: all global reads, no LDS dependencies ----
    // B-frags: built directly from W_ih (pre-scaled, bf16-packed, same
    // per-lane swizzle the old k_pre wrote). Gate f rows are skipped.
    union { uint4 u; bf16x8 v; } bfr[2][3];
    float biaL[2][3];
    #pragma unroll
    for (int ht2 = 0; ht2 < 2; ++ht2) {
        const int ht = 2 * w + ht2;
        #pragma unroll
        for (int g = 0; g < 3; ++g) {
            const int r  = g * 128 + ht * 16 + col;
            const int sr = r + (r >= 128 ? 128 : 0);
            const float sc = (g == 1) ? L2E2_ : L2E_;
            const f4* src = (const f4*)(W_ih + (size_t)n * 512 * L_ +
                                        (size_t)sr * L_ + quad * 8);
            f4 v0 = src[0] * sc, v1 = src[1] * sc;
            bfr[ht2][g].u.x = pk2bf(v0.x, v0.y);
            bfr[ht2][g].u.y = pk2bf(v0.z, v0.w);
            bfr[ht2][g].u.z = pk2bf(v1.x, v1.y);
            bfr[ht2][g].u.w = pk2bf(v1.z, v1.w);
            biaL[ht2][g] = (b_ih[(size_t)n * 512 + sr] +
                            b_hh[(size_t)n * 512 + sr]) * sc;
        }
    }
    {   // wsum partials: thread (jg=tid>>5, h4=tid&31) sums 16 j, coalesced
        const int h4 = tid & 31, jg = tid >> 5;
        const f4* Wf = (const f4*)(W_fc + (size_t)n * N_ * H_) +
                       (size_t)jg * 16 * 32 + h4;
        f4 s = {0.f, 0.f, 0.f, 0.f};
        #pragma unroll
        for (int j = 0; j < 16; ++j) s += Wf[j * 32];
        wpart[jg][h4] = s;
    }
    if (tid < 128) {   // bsum partials
        float bv = b_fc[n * N_ + tid];
        #pragma unroll
        for (int off = 32; off > 0; off >>= 1) bv += __shfl_down(bv, off, 64);
        if ((tid & 63) == 0) bp[tid >> 6] = bv;
    }
    // stage x
    xs[tid] = x[((size_t)b * N_ + n) * T_ + tid];
    if (tid < 2) xs[256 + tid] = 0.f;
    __syncthreads();

    // ---- phase B: derived from staged data ----
    if (tid < TT_) xr[tid] = 1.0f / xs[L_ + tid];
    if (tid < 128) {
        xeo[0][tid] = pk2bf(xs[2 * tid],     xs[2 * tid + 1]);
        xeo[1][tid] = pk2bf(xs[2 * tid + 1], xs[2 * tid + 2]);
    }
    if (tid < 32) {   // wsum reduce across jg partials
        f4 s = wpart[0][tid];
        #pragma unroll
        for (int jg = 1; jg < 8; ++jg) s += wpart[jg][tid];
        *(f4*)&ws_loc[tid * 4] = s;
    }
    if (tid == 0) bs_s = bp[0] + bp[1];
    __syncthreads();

    // ---- phase C: pre-build per-lane A-frags (conflicted pattern paid once)
    for (int e = tid; e < 14 * 64; e += 256) {
        const int tt = e >> 6, ln = e & 63;
        const int s  = tt * 16 + (ln & 15) + (ln >> 4) * 8;
        const int p  = s & 1, base = s >> 1;
        uint4 v;
        v.x = xeo[p][base + 0]; v.y = xeo[p][base + 1];
        v.z = xeo[p][base + 2]; v.w = xeo[p][base + 3];
        xA[e] = v;
    }
    __syncthreads();

    float wshL[2];
    wshL[0] = ws_loc[(2 * w + 0) * 16 + col];
    wshL[1] = ws_loc[(2 * w + 1) * 16 + col];
    const float bsum_n = bs_s;

    float hd_acc[2] = {0.f, 0.f};
    const f32x4 zero4 = {0.f, 0.f, 0.f, 0.f};

    #pragma unroll 2
    for (int ttile = 0; ttile < 14; ++ttile) {
        union { uint4 u; bf16x8 v; } af;
        af.u = xA[ttile * 64 + lane];          // one clean ds_read_b128

        const f4 xr4 = *(const f4*)&xr[ttile * 16 + quad * 4];
        float px[4];

        #pragma unroll
        for (int ht2 = 0; ht2 < 2; ++ht2) {
            f32x4 ai = __builtin_amdgcn_mfma_f32_16x16x32_bf16(af.v, bfr[ht2][0].v, zero4, 0, 0, 0);
            f32x4 ag = __builtin_amdgcn_mfma_f32_16x16x32_bf16(af.v, bfr[ht2][1].v, zero4, 0, 0, 0);
            f32x4 ao = __builtin_amdgcn_mfma_f32_16x16x32_bf16(af.v, bfr[ht2][2].v, zero4, 0, 0, 0);
            #pragma unroll
            for (int pr = 0; pr < 2; ++pr) {
                f2 gi = {ai[2*pr] + biaL[ht2][0], ai[2*pr+1] + biaL[ht2][0]};
                f2 gg = {ag[2*pr] + biaL[ht2][1], ag[2*pr+1] + biaL[ht2][1]};
                f2 go = {ao[2*pr] + biaL[ht2][2], ao[2*pr+1] + biaL[ht2][2]};
                f2 e1 = {aexp2n(gi.x), aexp2n(gi.y)};   // e^-gi
                f2 e2 = {aexp2(gg.x),  aexp2(gg.y)};    // e^2gg
                f2 e3 = {aexp2n(go.x), aexp2n(go.y)};   // e^-go
                const f2 A  = (1.f + e1) * (e2 + 1.f);
                const f2 Bv = 1.f + e3;
                const f2 AB = A * Bv;
                f2 R  = {arcp(AB.x), arcp(AB.y)};       // single merged rcp
                const f2 em = e2 - 1.f;
                const f2 t  = em * R;
                const f2 c  = t * Bv;                   // sig(gi)*tanh(gg)
                const f2 c2 = c * c;
                // tanh(c), |c|<=1: deg-7 odd (R12-verified coeffs)
                f2 Q = c2 * -0.027698f + 0.120833f;
                Q = c2 * Q - 0.331541f;
                Q = c2 * Q + 1.0f;
                const f2 hhv = t * Q;                   // sig(go)*tanh(c)
                hd_acc[ht2] = fmaf(hhv.x, xr4[2*pr],   hd_acc[ht2]);
                hd_acc[ht2] = fmaf(hhv.y, xr4[2*pr+1], hd_acc[ht2]);
                px[2*pr]   = hhv.x * wshL[ht2] + (ht2 ? px[2*pr]   : 0.f);
                px[2*pr+1] = hhv.y * wshL[ht2] + (ht2 ? px[2*pr+1] : 0.f);
            }
        }
        // X_hat partial: sum over this wave's 32 h (in-lane) then 16 n-lanes
        #pragma unroll
        for (int reg = 0; reg < 4; ++reg) {
            float pv = px[reg];
            pv += __shfl_xor(pv, 1, 64);
            pv += __shfl_xor(pv, 2, 64);
            pv += __shfl_xor(pv, 4, 64);
            pv += __shfl_xor(pv, 8, 64);
            if (col == 0) xh_part[w][ttile * 16 + quad * 4 + reg] = pv;
        }
    }

    // ---- Hd -> LDS (reduce across quads), Dinv partials ----
    #pragma unroll
    for (int ht2 = 0; ht2 < 2; ++ht2) {
        float v = hd_acc[ht2];
        v += __shfl_xor(v, 16, 64);
        v += __shfl_xor(v, 32, 64);
        if (lane < 16) hd_loc[(2 * w + ht2) * 16 + lane] = v;
    }
    {
        float dv = (tid < TT_) ? xr[tid] : 0.f;
        #pragma unroll
        for (int off = 32; off > 0; off >>= 1) dv += __shfl_down(dv, off, 64);
        if (lane == 0) red[w] = dv;
    }
    __syncthreads();

    // ---- X_hat writeout ----
    if (tid < TT_) {
        const float v = xh_part[0][tid] + xh_part[1][tid] +
                        xh_part[2][tid] + xh_part[3][tid];
        xhat[((size_t)b * TT_ + tid) * N_ + n] = v + bsum_n + 1e-6f;
    }

    // ---- fused G epilogue: thread pair (j, half) sums 64 h each ----
    {
        const float dinv = red[0] + red[1] + red[2] + red[3];
        const int j    = tid >> 1;
        const int half = tid & 1;
        const f4* Wf = (const f4*)(W_fc + ((size_t)n * N_ + j) * H_ + half * 64);
        float s = 0.f;
        #pragma unroll
        for (int q = 0; q < 16; ++q) {
            const f4 wv = Wf[q];
            const int hb = half * 64 + q * 4;
            s = fmaf(wv.x, hd_loc[hb + 0],
                fmaf(wv.y, hd_loc[hb + 1],
                fmaf(wv.z, hd_loc[hb + 2],
                fmaf(wv.w, hd_loc[hb + 3], s))));
        }
        s += __shfl_xor(s, 1, 64);
        if (half == 0) {
            const float bj = b_fc[n * N_ + j];
            G[(size_t)b * N_ * N_ + (size_t)j * N_ + n] =
                (s + bj * dinv) * (1.0f / 224.0f);
        }
    }
}

// ---------------------------------------------------------------------------
extern "C" void kernel_launch(void* const* d_in, const int* in_sizes, int n_in,
                              void* d_out, int out_size, void* d_ws, size_t ws_size,
                              hipStream_t stream) {
    const float* x    = (const float*)d_in[0];
    const float* W_ih = (const float*)d_in[1];
    const float* b_ih = (const float*)d_in[2];
    const float* b_hh = (const float*)d_in[3];
    const float* W_fc = (const float*)d_in[4];
    const float* b_fc = (const float*)d_in[5];

    float* G    = (float*)d_out;                        // B*N*N = 131072
    float* xhat = (float*)d_out + (size_t)B_ * N_ * N_; // B*TT*N = 229376

    (void)d_ws; (void)ws_size;   // workspace no longer used

    k_main<<<dim3(N_, B_), dim3(256), 0, stream>>>(x, W_ih, b_ih, b_hh,
                                                   W_fc, b_fc, G, xhat);
}

// Round 4
// 109.266 us; speedup vs baseline: 1.0239x; 1.0239x over previous
//
#include <hip/hip_runtime.h>
#include <math.h>

#define B_  8
#define N_  128
#define T_  256
#define L_  32
#define H_  128
#define TT_ 224   // T - L

typedef float f2    __attribute__((ext_vector_type(2)));
typedef float f4    __attribute__((ext_vector_type(4)));
typedef float f32x4 __attribute__((ext_vector_type(4)));
typedef short bf16x8 __attribute__((ext_vector_type(8)));

#define L2E_  1.4426950408889634f
#define L2E2_ 2.8853900817779268f

__device__ __forceinline__ unsigned pk2bf(float a, float b) {   // RNE bf16 pack
    unsigned ua = __float_as_uint(a), ub = __float_as_uint(b);
    ua = (ua + 0x7FFFu + ((ua >> 16) & 1u)) >> 16;
    ub = (ub + 0x7FFFu + ((ub >> 16) & 1u)) >> 16;
    return ua | (ub << 16);
}
__device__ __forceinline__ float aexp2(float x) {
    float r; asm("v_exp_f32 %0, %1" : "=v"(r) : "v"(x)); return r;
}
__device__ __forceinline__ float aexp2n(float x) {
    float r; asm("v_exp_f32 %0, -%1" : "=v"(r) : "v"(x)); return r;
}
__device__ __forceinline__ float arcp(float x) {
    return __builtin_amdgcn_rcpf(x);
}

// ---------------------------------------------------------------------------
// Single fused kernel, grid (N,B)=1024 x 256.
// R4 = R3 minus the LDS-staged MFMA C-operand bias (the NaN suspect by
// dataflow elimination):
//   - bias loaded DIRECTLY from global b_ih/b_hh as aligned f4 (same load
//     pattern R1 proved on W_ih), pre-scaled in registers,
//   - applied as explicit f32x4 add AFTER the MFMA; C operand is zero4
//     (exactly R1's proven MFMA usage),
//   - bia_s LDS array removed entirely.
// Swapped MFMA retained (proven safe given R1 passed on random data):
//   mfma(W_frag, x_frag, zero). Output col(lane&15)=t, row(quad*4+reg)=h_sub:
//   - X_hat's sum over h = in-lane FMAs + 2 shuffles/tile,
//   - hd's sum over t = in-lane across tiles, cross-col reduce paid once,
//   - xr is one ds_read_b32 per tile.
// Activation (unchanged algebra):
//   A=(1+e1)(e2+1), B=1+e3, R=rcp(A*B), t=em*R (em=e2-1),
//   c=t*B (= sig(gi)tanh(gg)), hh=t*Q(c^2) (= sig(go)*poly7tanh(c)).
// ---------------------------------------------------------------------------
__global__ __launch_bounds__(256)
__attribute__((amdgpu_waves_per_eu(4, 4)))
void k_main(const float* __restrict__ x,
            const float* __restrict__ W_ih,
            const float* __restrict__ b_ih, const float* __restrict__ b_hh,
            const float* __restrict__ W_fc, const float* __restrict__ b_fc,
            float* __restrict__ G, float* __restrict__ xhat) {
    const int n   = blockIdx.x;
    const int b   = blockIdx.y;
    const int tid = threadIdx.x;
    const int w    = tid >> 6;    // wave 0..3
    const int lane = tid & 63;
    const int col  = lane & 15;   // MFMA n index -> t_local
    const int quad = lane >> 4;   // MFMA k-group / row-group

    __shared__ __attribute__((aligned(16))) float xs[260];
    __shared__ __attribute__((aligned(16))) unsigned xeo[2][128];
    __shared__ __attribute__((aligned(16))) float xr[TT_];
    __shared__ uint4 xA[14 * 64];      // per-lane x-frags, 14 KB
    __shared__ __attribute__((aligned(16))) float xh_part[4][TT_];
    __shared__ __attribute__((aligned(16))) float hd_loc[H_];
    __shared__ float red[4];
    __shared__ f4 wpart[8][32];        // wsum partials, 4 KB
    __shared__ f4 ws4[32];             // wsum, natively 16B-aligned
    __shared__ float bp[2];
    __shared__ float bs_s;

    // ---- phase A: all global reads, no LDS read dependencies ----
    // W-frags: built directly from W_ih (pre-scaled, bf16-packed; per-lane
    // {own=lane&15, k=quad*8+j} layout, valid as A operand per R1 proof).
    union { uint4 u; bf16x8 v; } bfr[2][3];
    f32x4 biaR[2][3];   // per-row bias (registers, from GLOBAL loads)
    #pragma unroll
    for (int ht2 = 0; ht2 < 2; ++ht2) {
        const int ht = 2 * w + ht2;
        const int hb = ht * 16 + quad * 4;           // h-base of this lane's 4 rows
        #pragma unroll
        for (int g = 0; g < 3; ++g) {
            const int r  = g * 128 + ht * 16 + col;
            const int sr = r + (r >= 128 ? 128 : 0);
            const float sc = (g == 1) ? L2E2_ : L2E_;
            const f4* src = (const f4*)(W_ih + (size_t)n * 512 * L_ +
                                        (size_t)sr * L_ + quad * 8);
            f4 v0 = src[0] * sc, v1 = src[1] * sc;
            bfr[ht2][g].u.x = pk2bf(v0.x, v0.y);
            bfr[ht2][g].u.y = pk2bf(v0.z, v0.w);
            bfr[ht2][g].u.z = pk2bf(v1.x, v1.y);
            bfr[ht2][g].u.w = pk2bf(v1.z, v1.w);
            // bias rows for this lane's output rows (gate base: i=0,g=256,o=384)
            const int sg = (g == 0) ? 0 : (g == 1 ? 256 : 384);
            const f4 bi = *(const f4*)&b_ih[(size_t)n * 512 + sg + hb];
            const f4 bh = *(const f4*)&b_hh[(size_t)n * 512 + sg + hb];
            const f4 bs = (bi + bh) * sc;
            biaR[ht2][g][0] = bs.x; biaR[ht2][g][1] = bs.y;
            biaR[ht2][g][2] = bs.z; biaR[ht2][g][3] = bs.w;
        }
    }
    {   // wsum partials: thread (jg=tid>>5, h4=tid&31) sums 16 j, coalesced
        const int h4 = tid & 31, jg = tid >> 5;
        const f4* Wf = (const f4*)(W_fc + (size_t)n * N_ * H_) +
                       (size_t)jg * 16 * 32 + h4;
        f4 s = {0.f, 0.f, 0.f, 0.f};
        #pragma unroll
        for (int j = 0; j < 16; ++j) s += Wf[j * 32];
        wpart[jg][h4] = s;
    }
    if (tid < 128) {   // bsum partials
        float bv = b_fc[n * N_ + tid];
        #pragma unroll
        for (int off = 32; off > 0; off >>= 1) bv += __shfl_down(bv, off, 64);
        if ((tid & 63) == 0) bp[tid >> 6] = bv;
    }
    // stage x
    xs[tid] = x[((size_t)b * N_ + n) * T_ + tid];
    if (tid < 4) xs[256 + tid] = 0.f;
    __syncthreads();

    // ---- phase B: derived from staged data ----
    if (tid < TT_) xr[tid] = 1.0f / xs[L_ + tid];
    if (tid < 128) {
        xeo[0][tid] = pk2bf(xs[2 * tid],     xs[2 * tid + 1]);
        xeo[1][tid] = pk2bf(xs[2 * tid + 1], xs[2 * tid + 2]);
    }
    if (tid < 32) {   // wsum reduce across jg partials
        f4 s = wpart[0][tid];
        #pragma unroll
        for (int jg = 1; jg < 8; ++jg) s += wpart[jg][tid];
        ws4[tid] = s;
    }
    if (tid == 0) bs_s = bp[0] + bp[1];
    __syncthreads();

    // ---- phase C: pre-build per-lane x-frags (conflicted pattern paid once)
    for (int e = tid; e < 14 * 64; e += 256) {
        const int tt = e >> 6, ln = e & 63;
        const int s  = tt * 16 + (ln & 15) + (ln >> 4) * 8;
        const int p  = s & 1, base = s >> 1;
        uint4 v;
        v.x = xeo[p][base + 0]; v.y = xeo[p][base + 1];
        v.z = xeo[p][base + 2]; v.w = xeo[p][base + 3];
        xA[e] = v;
    }
    __syncthreads();

    // wsum for this lane's 4 output rows
    f4 wshF[2];
    #pragma unroll
    for (int ht2 = 0; ht2 < 2; ++ht2) {
        const int hb = (2 * w + ht2) * 16 + quad * 4;
        wshF[ht2] = ws4[hb >> 2];
    }
    const float bsum_n = bs_s;

    f32x4 hdacc[2] = {{0.f,0.f,0.f,0.f},{0.f,0.f,0.f,0.f}};
    const f32x4 zero4 = {0.f, 0.f, 0.f, 0.f};

    #pragma unroll 2
    for (int ttile = 0; ttile < 14; ++ttile) {
        union { uint4 u; bf16x8 v; } af;
        af.u = xA[ttile * 64 + lane];          // one clean ds_read_b128
        const float xrt = xr[ttile * 16 + col];

        float xsum = 0.f;
        #pragma unroll
        for (int ht2 = 0; ht2 < 2; ++ht2) {
            // swapped operands: A = W-frag (m=h_sub), B = x-frag (n=t), C = 0
            f32x4 gi = __builtin_amdgcn_mfma_f32_16x16x32_bf16(bfr[ht2][0].v, af.v, zero4, 0, 0, 0);
            f32x4 gg = __builtin_amdgcn_mfma_f32_16x16x32_bf16(bfr[ht2][1].v, af.v, zero4, 0, 0, 0);
            f32x4 go = __builtin_amdgcn_mfma_f32_16x16x32_bf16(bfr[ht2][2].v, af.v, zero4, 0, 0, 0);
            gi += biaR[ht2][0];                 // explicit per-row bias add
            gg += biaR[ht2][1];
            go += biaR[ht2][2];

            f32x4 e1, e2, e3;
            #pragma unroll
            for (int r = 0; r < 4; ++r) {
                e1[r] = aexp2n(gi[r]);          // e^-gi
                e2[r] = aexp2(gg[r]);           // e^2gg
                e3[r] = aexp2n(go[r]);          // e^-go
            }
            const f32x4 A  = (1.f + e1) * (e2 + 1.f);
            const f32x4 Bv = 1.f + e3;
            const f32x4 AB = A * Bv;
            f32x4 R;
            #pragma unroll
            for (int r = 0; r < 4; ++r) R[r] = arcp(AB[r]);
            const f32x4 em = e2 - 1.f;
            const f32x4 t  = em * R;
            const f32x4 c  = t * Bv;            // sig(gi)*tanh(gg)
            const f32x4 c2 = c * c;
            f32x4 Q = c2 * -0.027698f + 0.120833f;
            Q = c2 * Q - 0.331541f;
            Q = c2 * Q + 1.0f;
            const f32x4 hh = t * Q;             // sig(go)*tanh(c)

            hdacc[ht2] += hh * xrt;             // hd partial (sum over t in-lane)
            xsum = fmaf(hh[0], wshF[ht2][0],
                   fmaf(hh[1], wshF[ht2][1],
                   fmaf(hh[2], wshF[ht2][2],
                   fmaf(hh[3], wshF[ht2][3], xsum))));
        }
        // X_hat partial for t = ttile*16+col: sum over quads only
        xsum += __shfl_xor(xsum, 16, 64);
        xsum += __shfl_xor(xsum, 32, 64);
        if (lane < 16) xh_part[w][ttile * 16 + lane] = xsum;
    }

    // ---- Hd -> LDS: cross-col reduce paid once ----
    #pragma unroll
    for (int ht2 = 0; ht2 < 2; ++ht2) {
        #pragma unroll
        for (int r = 0; r < 4; ++r) {
            float v = hdacc[ht2][r];
            v += __shfl_xor(v, 1, 64);
            v += __shfl_xor(v, 2, 64);
            v += __shfl_xor(v, 4, 64);
            v += __shfl_xor(v, 8, 64);
            if (col == 0) hd_loc[(2 * w + ht2) * 16 + quad * 4 + r] = v;
        }
    }
    {
        float dv = (tid < TT_) ? xr[tid] : 0.f;
        #pragma unroll
        for (int off = 32; off > 0; off >>= 1) dv += __shfl_down(dv, off, 64);
        if (lane == 0) red[w] = dv;
    }
    __syncthreads();

    // ---- X_hat writeout ----
    if (tid < TT_) {
        const float v = xh_part[0][tid] + xh_part[1][tid] +
                        xh_part[2][tid] + xh_part[3][tid];
        xhat[((size_t)b * TT_ + tid) * N_ + n] = v + bsum_n + 1e-6f;
    }

    // ---- fused G epilogue: thread pair (j, half) sums 64 h each ----
    {
        const float dinv = red[0] + red[1] + red[2] + red[3];
        const int j    = tid >> 1;
        const int half = tid & 1;
        const f4* Wf = (const f4*)(W_fc + ((size_t)n * N_ + j) * H_ + half * 64);
        float s = 0.f;
        #pragma unroll
        for (int q = 0; q < 16; ++q) {
            const f4 wv = Wf[q];
            const int hb = half * 64 + q * 4;
            s = fmaf(wv.x, hd_loc[hb + 0],
                fmaf(wv.y, hd_loc[hb + 1],
                fmaf(wv.z, hd_loc[hb + 2],
                fmaf(wv.w, hd_loc[hb + 3], s))));
        }
        s += __shfl_xor(s, 1, 64);
        if (half == 0) {
            const float bj = b_fc[n * N_ + j];
            G[(size_t)b * N_ * N_ + (size_t)j * N_ + n] =
                (s + bj * dinv) * (1.0f / 224.0f);
        }
    }
}

// ---------------------------------------------------------------------------
extern "C" void kernel_launch(void* const* d_in, const int* in_sizes, int n_in,
                              void* d_out, int out_size, void* d_ws, size_t ws_size,
                              hipStream_t stream) {
    const float* x    = (const float*)d_in[0];
    const float* W_ih = (const float*)d_in[1];
    const float* b_ih = (const float*)d_in[2];
    const float* b_hh = (const float*)d_in[3];
    const float* W_fc = (const float*)d_in[4];
    const float* b_fc = (const float*)d_in[5];

    float* G    = (float*)d_out;                        // B*N*N = 131072
    float* xhat = (float*)d_out + (size_t)B_ * N_ * N_; // B*TT*N = 229376

    (void)d_ws; (void)ws_size;   // workspace unused

    k_main<<<dim3(N_, B_), dim3(256), 0, stream>>>(x, W_ih, b_ih, b_hh,
                                                   W_fc, b_fc, G, xhat);
}